// Round 1
// baseline (662.999 us; speedup 1.0000x reference)
//
#include <hip/hip_runtime.h>
#include <hip/hip_bf16.h>
#include <math.h>

#define PI_F 3.14159265358979323846f

// ---------------------------------------------------------------------------
// Shapes: x (8,64,256,256) f32; weight_fft (64,64,256,129) f32; bias (64) f32
// y (8,64,256,256) f32.
// Workspace: Xf complex interleaved (B=8, C=64, H=256, Wf=129) float2 = 516MB
// ---------------------------------------------------------------------------

__device__ __forceinline__ unsigned brev8(unsigned v) { return __brev(v) >> 24; }

// ---------------- Pass 1: row rfft (256 real -> 129 complex) ----------------
// One block of 256 threads per row. DIT radix-2, bit-reversal folded into
// stage-1 reads.
__global__ __launch_bounds__(256) void k_rowfft(const float* __restrict__ x,
                                                float2* __restrict__ Xf) {
    __shared__ float2 a[256];
    const int row = blockIdx.x;                 // (b*64+c)*256 + h
    const int t = threadIdx.x;
    const float* xr = x + (size_t)row * 256;
    a[t] = make_float2(xr[t], 0.0f);
    __syncthreads();
#pragma unroll
    for (int s = 1; s <= 8; ++s) {
        const int half = 1 << (s - 1);
        const int p = t & ~half, q = p | half;
        const int j = t & (half - 1);
        const int rp = (s == 1) ? (int)brev8(p) : p;
        const int rq = (s == 1) ? (int)brev8(q) : q;
        float2 u = a[rp], v = a[rq];
        float sn, cs;
        __sincosf(-PI_F * (float)j / (float)half, &sn, &cs);
        float2 wv = make_float2(cs * v.x - sn * v.y, cs * v.y + sn * v.x);
        const float sig = (t & half) ? -1.0f : 1.0f;
        float2 o = make_float2(u.x + sig * wv.x, u.y + sig * wv.y);
        __syncthreads();
        a[t] = o;
        __syncthreads();
    }
    if (t <= 128) Xf[(size_t)row * 129 + t] = a[t];
}

// ------------- Pass 2/4: column FFT along H (in-place, tiled) ---------------
// Block = (b*64+c, w-tile of <=16 columns). LDS a[16][257] (padded).
__global__ __launch_bounds__(256) void k_colfft(float2* __restrict__ Xf,
                                                float sgn) {
    __shared__ float2 a[16][257];
    const int wt = blockIdx.x;
    const int w0 = wt * 16;
    const int TW = min(16, 129 - w0);
    const size_t base = (size_t)blockIdx.y * 256 * 129;
    const int t = threadIdx.x;
    const int wl = t & 15, hb = t >> 4;

#pragma unroll
    for (int it = 0; it < 16; ++it) {
        const int h = it * 16 + hb;
        if (wl < TW) a[wl][h] = Xf[base + (size_t)h * 129 + w0 + wl];
    }
    __syncthreads();

#pragma unroll
    for (int s = 1; s <= 8; ++s) {
        const int half = 1 << (s - 1);
        const int p = t & ~half, q = p | half;
        const int j = t & (half - 1);
        const int rp = (s == 1) ? (int)brev8(p) : p;
        const int rq = (s == 1) ? (int)brev8(q) : q;
        float sn, cs;
        __sincosf(sgn * PI_F * (float)j / (float)half, &sn, &cs);
        const float sig = (t & half) ? -1.0f : 1.0f;
        float2 u[16], v[16];
#pragma unroll
        for (int c = 0; c < 16; ++c)
            if (c < TW) { u[c] = a[c][rp]; v[c] = a[c][rq]; }
        __syncthreads();
#pragma unroll
        for (int c = 0; c < 16; ++c)
            if (c < TW) {
                float2 wv = make_float2(cs * v[c].x - sn * v[c].y,
                                        cs * v[c].y + sn * v[c].x);
                a[c][t] = make_float2(u[c].x + sig * wv.x, u[c].y + sig * wv.y);
            }
        __syncthreads();
    }

#pragma unroll
    for (int it = 0; it < 16; ++it) {
        const int h = it * 16 + hb;
        if (wl < TW) Xf[base + (size_t)h * 129 + w0 + wl] = a[wl][h];
    }
}

// --------------------- Pass 3: per-bin einsum (in-place) --------------------
// Z[b,i,h,w] = sum_o X[b,o,h,w] * W[o,i,h,w]   (W real)
// Block = (h, w-tile of 16). X tile (8b x 64o x 16w complex) staged in 64KB
// LDS; each thread owns (wl, j) and accumulates 4 i-values x 8 b in regs, so
// each W element is loaded exactly once per call.
__global__ __launch_bounds__(256) void k_einsum(float2* __restrict__ Xf,
                                                const float* __restrict__ Wt) {
    __shared__ float2 xs[512][16];              // [(b<<6)|o][wl] = 64 KB
    const int t = threadIdx.x;
    // XCD-chunked swizzle: 2304 blocks, 288 consecutive per XCD.
    const int bid = blockIdx.x;
    const int nid = (bid & 7) * 288 + (bid >> 3);
    const int wt = nid % 9;
    const int h = nid / 9;
    const int w0 = wt * 16;
    const int TW = min(16, 129 - w0);

    // stage X[*, *, h, w0:w0+TW] into LDS
#pragma unroll
    for (int k = 0; k < 32; ++k) {
        const int e = t + 256 * k;              // 8192 = 512 pairs * 16 w
        const int pr = e >> 4, wl = e & 15;
        if (wl < TW)
            xs[pr][wl] = Xf[((size_t)pr * 256 + h) * 129 + w0 + wl];
    }
    __syncthreads();

    const int wl = t & 15, j = t >> 4;
    float2 acc[4][8];
#pragma unroll
    for (int r = 0; r < 4; ++r)
#pragma unroll
        for (int b = 0; b < 8; ++b) acc[r][b] = make_float2(0.0f, 0.0f);

    if (wl < TW) {
        const float* Wh = Wt + (size_t)h * 129 + w0 + wl;
        for (int o = 0; o < 64; ++o) {
            float2 xv[8];
#pragma unroll
            for (int b = 0; b < 8; ++b) xv[b] = xs[(b << 6) | o][wl];
#pragma unroll
            for (int r = 0; r < 4; ++r) {
                const int i = j + (r << 4);
                const float wv = Wh[(size_t)((o << 6) | i) * 33024];
#pragma unroll
                for (int b = 0; b < 8; ++b) {
                    acc[r][b].x += xv[b].x * wv;
                    acc[r][b].y += xv[b].y * wv;
                }
            }
        }
    }
    __syncthreads();

    if (wl < TW) {
#pragma unroll
        for (int r = 0; r < 4; ++r) {
            const int i = j + (r << 4);
#pragma unroll
            for (int b = 0; b < 8; ++b) {
                Xf[((size_t)((b << 6) | i) * 256 + h) * 129 + w0 + wl] =
                    acc[r][b];
            }
        }
    }
}

// ------------- Pass 5: row irfft (129 complex -> 256 real) + bias -----------
__global__ __launch_bounds__(256) void k_rowifft(const float2* __restrict__ Zf,
                                                 const float* __restrict__ bias,
                                                 float* __restrict__ y) {
    __shared__ float2 a[256];
    const int row = blockIdx.x;                 // (b*64+i)*256 + h
    const int ci = (row >> 8) & 63;
    const int t = threadIdx.x;
    const float2* zr = Zf + (size_t)row * 129;
    if (t <= 128) {
        float2 v = zr[t];
        a[t] = v;
        if (t >= 1 && t <= 127) a[256 - t] = make_float2(v.x, -v.y);
    }
    __syncthreads();
#pragma unroll
    for (int s = 1; s <= 8; ++s) {
        const int half = 1 << (s - 1);
        const int p = t & ~half, q = p | half;
        const int j = t & (half - 1);
        const int rp = (s == 1) ? (int)brev8(p) : p;
        const int rq = (s == 1) ? (int)brev8(q) : q;
        float2 u = a[rp], v = a[rq];
        float sn, cs;
        __sincosf(PI_F * (float)j / (float)half, &sn, &cs);
        float2 wv = make_float2(cs * v.x - sn * v.y, cs * v.y + sn * v.x);
        const float sig = (t & half) ? -1.0f : 1.0f;
        float2 o = make_float2(u.x + sig * wv.x, u.y + sig * wv.y);
        __syncthreads();
        a[t] = o;
        __syncthreads();
    }
    const float b = bias[ci];
    y[(size_t)row * 256 + t] = a[t].x * (1.0f / 65536.0f) + b;
}

// ---------------------------------------------------------------------------
extern "C" void kernel_launch(void* const* d_in, const int* in_sizes, int n_in,
                              void* d_out, int out_size, void* d_ws,
                              size_t ws_size, hipStream_t stream) {
    (void)in_sizes; (void)n_in; (void)out_size; (void)ws_size;
    const float* x    = (const float*)d_in[0];
    const float* wfft = (const float*)d_in[1];
    const float* bias = (const float*)d_in[2];
    float* y = (float*)d_out;
    float2* Xf = (float2*)d_ws;                 // 8*64*256*129 float2 = 516 MB

    const int ROWS = 8 * 64 * 256;              // 131072

    k_rowfft<<<ROWS, 256, 0, stream>>>(x, Xf);
    k_colfft<<<dim3(9, 512), 256, 0, stream>>>(Xf, -1.0f);
    k_einsum<<<2304, 256, 0, stream>>>(Xf, wfft);
    k_colfft<<<dim3(9, 512), 256, 0, stream>>>(Xf, +1.0f);
    k_rowifft<<<ROWS, 256, 0, stream>>>(Xf, bias, y);
}

// Round 2
// 586.064 us; speedup vs baseline: 1.1313x; 1.1313x over previous
//
#include <hip/hip_runtime.h>
#include <hip/hip_bf16.h>
#include <math.h>

#define PI_F 3.14159265358979323846f

// ---------------------------------------------------------------------------
// Shapes: x (8,64,256,256) f32; weight_fft (64,64,256,129) f32; bias (64) f32
// y (8,64,256,256) f32.
// Workspace: Xf complex packed-bf16 (B=8,C=64,H=256,Wf=129) uint = 258 MB
//   (lo 16 bits = real bf16, hi 16 bits = imag bf16)
// All FFT/einsum arithmetic is fp32; only inter-pass storage is bf16.
// ---------------------------------------------------------------------------

__device__ __forceinline__ unsigned brev8(unsigned v) { return __brev(v) >> 24; }

__device__ __forceinline__ unsigned pack_bf(float re, float im) {
    unsigned ur = __float_as_uint(re);
    unsigned ui = __float_as_uint(im);
    ur = (ur + 0x7fffu + ((ur >> 16) & 1u)) >> 16;     // RNE to bf16
    ui = (ui + 0x7fffu + ((ui >> 16) & 1u)) & 0xffff0000u;
    return ur | ui;
}
__device__ __forceinline__ float2 unpack_bf(unsigned p) {
    return make_float2(__uint_as_float(p << 16),
                       __uint_as_float(p & 0xffff0000u));
}

// ---------------- Pass 1: row rfft (256 real -> 129 complex) ----------------
__global__ __launch_bounds__(256) void k_rowfft(const float* __restrict__ x,
                                                unsigned* __restrict__ Xf) {
    __shared__ float2 a[256];
    const int row = blockIdx.x;                 // (b*64+c)*256 + h
    const int t = threadIdx.x;
    const float* xr = x + (size_t)row * 256;
    a[t] = make_float2(xr[t], 0.0f);
    __syncthreads();
#pragma unroll
    for (int s = 1; s <= 8; ++s) {
        const int half = 1 << (s - 1);
        const int p = t & ~half, q = p | half;
        const int j = t & (half - 1);
        const int rp = (s == 1) ? (int)brev8(p) : p;
        const int rq = (s == 1) ? (int)brev8(q) : q;
        float2 u = a[rp], v = a[rq];
        float sn, cs;
        __sincosf(-PI_F * (float)j / (float)half, &sn, &cs);
        float2 wv = make_float2(cs * v.x - sn * v.y, cs * v.y + sn * v.x);
        const float sig = (t & half) ? -1.0f : 1.0f;
        float2 o = make_float2(u.x + sig * wv.x, u.y + sig * wv.y);
        __syncthreads();
        a[t] = o;
        __syncthreads();
    }
    if (t <= 128) Xf[(size_t)row * 129 + t] = pack_bf(a[t].x, a[t].y);
}

// ------------- Pass 2/4: column FFT along H (in-place, tiled) ---------------
// Block = (b*64+c, w-tile of <=16 columns). LDS a[16][257] (padded).
__global__ __launch_bounds__(256) void k_colfft(unsigned* __restrict__ Xf,
                                                float sgn) {
    __shared__ float2 a[16][257];
    const int wt = blockIdx.x;
    const int w0 = wt * 16;
    const int TW = min(16, 129 - w0);
    const size_t base = (size_t)blockIdx.y * 256 * 129;
    const int t = threadIdx.x;
    const int wl = t & 15, hb = t >> 4;

#pragma unroll
    for (int it = 0; it < 16; ++it) {
        const int h = it * 16 + hb;
        if (wl < TW) a[wl][h] = unpack_bf(Xf[base + (size_t)h * 129 + w0 + wl]);
    }
    __syncthreads();

#pragma unroll
    for (int s = 1; s <= 8; ++s) {
        const int half = 1 << (s - 1);
        const int p = t & ~half, q = p | half;
        const int j = t & (half - 1);
        const int rp = (s == 1) ? (int)brev8(p) : p;
        const int rq = (s == 1) ? (int)brev8(q) : q;
        float sn, cs;
        __sincosf(sgn * PI_F * (float)j / (float)half, &sn, &cs);
        const float sig = (t & half) ? -1.0f : 1.0f;
        float2 u[16], v[16];
#pragma unroll
        for (int c = 0; c < 16; ++c)
            if (c < TW) { u[c] = a[c][rp]; v[c] = a[c][rq]; }
        __syncthreads();
#pragma unroll
        for (int c = 0; c < 16; ++c)
            if (c < TW) {
                float2 wv = make_float2(cs * v[c].x - sn * v[c].y,
                                        cs * v[c].y + sn * v[c].x);
                a[c][t] = make_float2(u[c].x + sig * wv.x, u[c].y + sig * wv.y);
            }
        __syncthreads();
    }

#pragma unroll
    for (int it = 0; it < 16; ++it) {
        const int h = it * 16 + hb;
        if (wl < TW)
            Xf[base + (size_t)h * 129 + w0 + wl] = pack_bf(a[wl][h].x, a[wl][h].y);
    }
}

// --------------------- Pass 3: per-bin einsum (in-place) --------------------
// Z[b,i,h,w] = sum_o X[b,o,h,w] * W[o,i,h,w]   (W real)
__global__ __launch_bounds__(256) void k_einsum(unsigned* __restrict__ Xf,
                                                const float* __restrict__ Wt) {
    __shared__ float2 xs[512][16];              // [(b<<6)|o][wl] = 64 KB fp32
    const int t = threadIdx.x;
    // XCD-chunked swizzle: 2304 blocks, 288 consecutive per XCD.
    const int bid = blockIdx.x;
    const int nid = (bid & 7) * 288 + (bid >> 3);
    const int wt = nid % 9;
    const int h = nid / 9;
    const int w0 = wt * 16;
    const int TW = min(16, 129 - w0);

    // stage X[*, *, h, w0:w0+TW] into LDS (unpack bf16 -> fp32)
#pragma unroll
    for (int k = 0; k < 32; ++k) {
        const int e = t + 256 * k;              // 8192 = 512 pairs * 16 w
        const int pr = e >> 4, wl = e & 15;
        if (wl < TW)
            xs[pr][wl] = unpack_bf(Xf[((size_t)pr * 256 + h) * 129 + w0 + wl]);
    }
    __syncthreads();

    const int wl = t & 15, j = t >> 4;
    float2 acc[4][8];
#pragma unroll
    for (int r = 0; r < 4; ++r)
#pragma unroll
        for (int b = 0; b < 8; ++b) acc[r][b] = make_float2(0.0f, 0.0f);

    if (wl < TW) {
        const float* Wh = Wt + (size_t)h * 129 + w0 + wl;
        for (int o = 0; o < 64; ++o) {
            float2 xv[8];
#pragma unroll
            for (int b = 0; b < 8; ++b) xv[b] = xs[(b << 6) | o][wl];
#pragma unroll
            for (int r = 0; r < 4; ++r) {
                const int i = j + (r << 4);
                const float wv = Wh[(size_t)((o << 6) | i) * 33024];
#pragma unroll
                for (int b = 0; b < 8; ++b) {
                    acc[r][b].x += xv[b].x * wv;
                    acc[r][b].y += xv[b].y * wv;
                }
            }
        }
    }
    __syncthreads();

    if (wl < TW) {
#pragma unroll
        for (int r = 0; r < 4; ++r) {
            const int i = j + (r << 4);
#pragma unroll
            for (int b = 0; b < 8; ++b) {
                Xf[((size_t)((b << 6) | i) * 256 + h) * 129 + w0 + wl] =
                    pack_bf(acc[r][b].x, acc[r][b].y);
            }
        }
    }
}

// ------------- Pass 5: row irfft (129 complex -> 256 real) + bias -----------
__global__ __launch_bounds__(256) void k_rowifft(const unsigned* __restrict__ Zf,
                                                 const float* __restrict__ bias,
                                                 float* __restrict__ y) {
    __shared__ float2 a[256];
    const int row = blockIdx.x;                 // (b*64+i)*256 + h
    const int ci = (row >> 8) & 63;
    const int t = threadIdx.x;
    const unsigned* zr = Zf + (size_t)row * 129;
    if (t <= 128) {
        float2 v = unpack_bf(zr[t]);
        a[t] = v;
        if (t >= 1 && t <= 127) a[256 - t] = make_float2(v.x, -v.y);
    }
    __syncthreads();
#pragma unroll
    for (int s = 1; s <= 8; ++s) {
        const int half = 1 << (s - 1);
        const int p = t & ~half, q = p | half;
        const int j = t & (half - 1);
        const int rp = (s == 1) ? (int)brev8(p) : p;
        const int rq = (s == 1) ? (int)brev8(q) : q;
        float2 u = a[rp], v = a[rq];
        float sn, cs;
        __sincosf(PI_F * (float)j / (float)half, &sn, &cs);
        float2 wv = make_float2(cs * v.x - sn * v.y, cs * v.y + sn * v.x);
        const float sig = (t & half) ? -1.0f : 1.0f;
        float2 o = make_float2(u.x + sig * wv.x, u.y + sig * wv.y);
        __syncthreads();
        a[t] = o;
        __syncthreads();
    }
    const float b = bias[ci];
    y[(size_t)row * 256 + t] = a[t].x * (1.0f / 65536.0f) + b;
}

// ---------------------------------------------------------------------------
extern "C" void kernel_launch(void* const* d_in, const int* in_sizes, int n_in,
                              void* d_out, int out_size, void* d_ws,
                              size_t ws_size, hipStream_t stream) {
    (void)in_sizes; (void)n_in; (void)out_size; (void)ws_size;
    const float* x    = (const float*)d_in[0];
    const float* wfft = (const float*)d_in[1];
    const float* bias = (const float*)d_in[2];
    float* y = (float*)d_out;
    unsigned* Xf = (unsigned*)d_ws;             // 8*64*256*129 uint = 258 MB

    const int ROWS = 8 * 64 * 256;              // 131072

    k_rowfft<<<ROWS, 256, 0, stream>>>(x, Xf);
    k_colfft<<<dim3(9, 512), 256, 0, stream>>>(Xf, -1.0f);
    k_einsum<<<2304, 256, 0, stream>>>(Xf, wfft);
    k_colfft<<<dim3(9, 512), 256, 0, stream>>>(Xf, +1.0f);
    k_rowifft<<<ROWS, 256, 0, stream>>>(Xf, bias, y);
}